// Round 11
// baseline (1266.790 us; speedup 1.0000x reference)
//
#include <hip/hip_runtime.h>
#include <hip/hip_fp16.h>
#include <cstdint>
#include <cstddef>

// LSTM: B=32, T=1024, D=1024, H=128, gates 4H=512 (order i,f,g,o).
//   prep:     W_ih fp32->fp16, W_hh fp32->fp16, bsum = b_ih + b_hh
//   gemm_gx:  gx[32768][512] = x @ W_ih^T + bsum   (fp16 MFMA, fp32 acc)
//   lstm_rec (r11): MFMA recurrence, 2 blocks x 16 batches each.
//   r10 lesson: per-step wall (~1680cy) is the barrier-locked serial chain,
//   not issue count (LDS 4x cut: flat; weight residency: flat). Fix:
//   amortize ONE chain over 16 batches via MFMA G = W_hh @ h[128x16].
//   Wave w owns M-tiles {w,w+8,w+16,w+24} = i,f,g,o rows of the same j's ->
//   all 4 gates of (j,beta) land IN-LANE (D: col=lane&15=batch,
//   row=4*(lane>>4)+reg). Weights = A-frags, 64 dwords/lane pinned (r9
//   pattern). gx = MFMA C-init, prefetched 1 step ahead. h -> LDS pitch-136
//   (2-way conflicts only). One lgkm-only barrier/step (proven).

typedef __attribute__((ext_vector_type(8))) _Float16 half8;
typedef __attribute__((ext_vector_type(4))) _Float16 half4;
typedef __attribute__((ext_vector_type(4))) float    f32x4;
typedef __attribute__((ext_vector_type(4))) unsigned int u32x4;

#define BT    32768   // B*T
#define DD    1024
#define GG    512     // 4*H
#define HH    128
#define TT    1024
#define BB    32

// ---------------- prep: fp16 conversions + bias sum ----------------
__global__ void prep_kernel(const float* __restrict__ wih,
                            const float* __restrict__ whh,
                            const float* __restrict__ bih,
                            const float* __restrict__ bhh,
                            _Float16* __restrict__ wih_h,
                            __half*   __restrict__ whh_h,
                            float* __restrict__ bsum) {
    int i = blockIdx.x * 256 + threadIdx.x;   // grid covers 512*1024 exactly
    wih_h[i] = (_Float16)wih[i];
    if (i < GG * HH) whh_h[i] = __float2half(whh[i]);
    if (i < GG)      bsum[i] = bih[i] + bhh[i];
}

// ---------------- GEMM: gx = x @ W_ih^T + bsum (unchanged, verified) --------
#define BM 128
#define BN 128
#define BK 32
#define LDP 40   // LDS row pitch in halves (80B rows, 2-way bank alias = free)

__global__ __launch_bounds__(256)
void gemm_gx(const float* __restrict__ x, const _Float16* __restrict__ wih_h,
             const float* __restrict__ bsum, float* __restrict__ gx) {
    const int bid = blockIdx.x;
    const int m0 = (bid >> 2) * BM;
    const int n0 = (bid & 3) * BN;
    const int t  = threadIdx.x;
    const int lane = t & 63;
    const int w  = t >> 6;
    const int wr = w >> 1, wc = w & 1;
    const int lr = lane & 15;
    const int lk = lane >> 4;

    __shared__ __align__(16) _Float16 As[BM][LDP];
    __shared__ __align__(16) _Float16 Bs[BN][LDP];

    f32x4 acc[4][4] = {};

    for (int kt = 0; kt < DD; kt += BK) {
        #pragma unroll
        for (int pass = 0; pass < 4; ++pass) {
            int r = pass * 32 + (t >> 3);
            int c = (t & 7) * 4;
            float4 v = *(const float4*)(x + (size_t)(m0 + r) * DD + kt + c);
            half4 hv;
            hv[0] = (_Float16)v.x; hv[1] = (_Float16)v.y;
            hv[2] = (_Float16)v.z; hv[3] = (_Float16)v.w;
            *(half4*)&As[r][c] = hv;
        }
        #pragma unroll
        for (int pass = 0; pass < 2; ++pass) {
            int r = pass * 64 + (t >> 2);
            int c = (t & 3) * 8;
            float4 v = *(const float4*)(wih_h + (size_t)(n0 + r) * DD + kt + c);
            *(float4*)&Bs[r][c] = v;
        }
        __syncthreads();

        half8 af[4], bf[4];
        #pragma unroll
        for (int i = 0; i < 4; ++i)
            af[i] = *(const half8*)&As[wr * 64 + i * 16 + lr][lk * 8];
        #pragma unroll
        for (int j = 0; j < 4; ++j)
            bf[j] = *(const half8*)&Bs[wc * 64 + j * 16 + lr][lk * 8];

        #pragma unroll
        for (int i = 0; i < 4; ++i)
            #pragma unroll
            for (int j = 0; j < 4; ++j)
                acc[i][j] = __builtin_amdgcn_mfma_f32_16x16x32_f16(af[i], bf[j], acc[i][j], 0, 0, 0);
        __syncthreads();
    }

    #pragma unroll
    for (int j = 0; j < 4; ++j) {
        int n = n0 + wc * 64 + j * 16 + lr;
        float bn = bsum[n];
        #pragma unroll
        for (int i = 0; i < 4; ++i) {
            int mbase = m0 + wr * 64 + i * 16 + lk * 4;
            #pragma unroll
            for (int r = 0; r < 4; ++r)
                gx[(size_t)(mbase + r) * GG + n] = acc[i][j][r] + bn;
        }
    }
}

// ---------------- recurrence (MFMA, 16 batches/block) ----------------
__device__ __forceinline__ half8 as_h8(u32x4 v) {
    union { u32x4 u; half8 h; } x; x.u = v; return x.h;
}

#define LOG2E 1.4426950408889634f
#define SIG(x) __builtin_amdgcn_rcpf(1.f + __builtin_amdgcn_exp2f(-LOG2E * (x)))
#define TNH(x) fmaf(2.f, __builtin_amdgcn_rcpf(1.f + __builtin_amdgcn_exp2f(-2.f * LOG2E * (x))), -1.f)

// weights: A-frag for gate G, K-chunk K: row = G*128 + 16w + (lane&15),
// k = K*32 + 8*(lane>>4). 16 named u32x4 (64 dwords), pinned (r9 pattern).
#define WLD(G,K) u32x4 w##G##_##K = *(const u32x4*)(whh_h + \
    (size_t)(((G) * 128 + w16 + beta) * 128 + (K) * 32 + lk8));
#define WPN(G,K) asm volatile("" : "+v"(w##G##_##K));
#define WFOR(F) F(0,0) F(0,1) F(0,2) F(0,3) F(1,0) F(1,1) F(1,2) F(1,3) \
                F(2,0) F(2,1) F(2,2) F(2,3) F(3,0) F(3,1) F(3,2) F(3,3)

// per-row state update: all 4 gates of (j0+R, beta) are in-lane
#define CHR(R) { \
    float i_ = SIG(A0[R]), f_ = SIG(A1[R]), g_ = TNH(A2[R]), o_ = SIG(A3[R]); \
    c##R = fmaf(f_, c##R, i_ * g_); \
    h##R = o_ * TNH(c##R); }

#define MFMA_(W,B,A) A = __builtin_amdgcn_mfma_f32_16x16x32_f16(as_h8(W), B, A, 0, 0, 0)

#define STEP(CURB, NXTB, GC, GN, PF) { \
    /* prefetch next-step gx (independent of the recurrence chain) */ \
    if (PF) { \
        gp += 512; \
        gx##GN##0 = *(const f32x4*)(gp); \
        gx##GN##1 = *(const f32x4*)(gp + 128); \
        gx##GN##2 = *(const f32x4*)(gp + 256); \
        gx##GN##3 = *(const f32x4*)(gp + 384); \
    } \
    /* B-frags: h_lds[CURB][beta][K*32 + 8*lk .. +8) */ \
    half8 b0_ = *(const half8*)(hrd + (CURB) * 4352 + 0); \
    half8 b1_ = *(const half8*)(hrd + (CURB) * 4352 + 64); \
    half8 b2_ = *(const half8*)(hrd + (CURB) * 4352 + 128); \
    half8 b3_ = *(const half8*)(hrd + (CURB) * 4352 + 192); \
    /* 16 MFMA: 4 independent gate chains, C-init = gx */ \
    f32x4 A0 = gx##GC##0, A1 = gx##GC##1, A2 = gx##GC##2, A3 = gx##GC##3; \
    MFMA_(w0_0, b0_, A0); MFMA_(w1_0, b0_, A1); MFMA_(w2_0, b0_, A2); MFMA_(w3_0, b0_, A3); \
    MFMA_(w0_1, b1_, A0); MFMA_(w1_1, b1_, A1); MFMA_(w2_1, b1_, A2); MFMA_(w3_1, b1_, A3); \
    MFMA_(w0_2, b2_, A0); MFMA_(w1_2, b2_, A1); MFMA_(w2_2, b2_, A2); MFMA_(w3_2, b2_, A3); \
    MFMA_(w0_3, b3_, A0); MFMA_(w1_3, b3_, A1); MFMA_(w2_3, b3_, A2); MFMA_(w3_3, b3_, A3); \
    /* activations + c/h update (in-lane, no exchange) */ \
    CHR(0) CHR(1) CHR(2) CHR(3) \
    /* h -> fp16 -> h_lds[NXTB][beta][j0..j0+3] */ \
    { __half2 q01 = __floats2half2_rn(h0, h1), q23 = __floats2half2_rn(h2, h3); \
      uint2 qq; qq.x = *(uint32_t*)&q01; qq.y = *(uint32_t*)&q23; \
      *(uint2*)(hwr + (NXTB) * 4352) = qq; } \
    /* out store, fire-and-forget (vmcnt stays off the lgkm chain) */ \
    { f32x4 oh; oh[0] = h0; oh[1] = h1; oh[2] = h2; oh[3] = h3; \
      *(f32x4*)outp = oh; outp += HH; } \
    /* one barrier per step: LDS-only drain */ \
    __builtin_amdgcn_sched_barrier(0); \
    asm volatile("s_waitcnt lgkmcnt(0)" ::: "memory"); \
    __builtin_amdgcn_s_barrier(); \
    __builtin_amdgcn_sched_barrier(0); \
}

__global__ __launch_bounds__(512)
__attribute__((amdgpu_waves_per_eu(2, 2)))
void lstm_rec(const float* __restrict__ gx, const __half* __restrict__ whh_h,
              float* __restrict__ out, float* __restrict__ hn, float* __restrict__ cn) {
    const int t    = threadIdx.x;
    const int w    = t >> 6;        // wave 0..7 -> M-tiles {w, w+8, w+16, w+24}
    const int lane = t & 63;
    const int beta = lane & 15;     // batch within block (A-row / B-col / D-col)
    const int lk   = lane >> 4;     // k-chunk group / D-row group
    const int w16  = w << 4;
    const int lk8  = lk << 3;
    const int j0   = w16 + (lk << 2);          // this lane's 4 hidden rows
    const int b0g  = blockIdx.x * 16;          // global batch base

    // h state, double-buffered, pitch 136 halves (272B -> 2-way banks, free)
    __shared__ __align__(16) _Float16 hls[2][16][136];

    WFOR(WLD)
    WFOR(WPN)

    for (int i = t; i < 2 * 16 * 136; i += 512)
        ((_Float16*)hls)[i] = (_Float16)0.f;
    __syncthreads();

    const char* hrd = (const char*)hls + beta * 272 + lk * 16;  // B-frag base
    char*       hwr = (char*)hls + beta * 272 + j0 * 2;         // h write base

    const float* gp   = gx  + (size_t)(b0g + beta) * TT * GG + j0;
    float*       outp = out + (size_t)(b0g + beta) * TT * HH + j0;

    float c0 = 0.f, c1 = 0.f, c2 = 0.f, c3 = 0.f;
    float h0 = 0.f, h1 = 0.f, h2 = 0.f, h3 = 0.f;

    f32x4 gxa0, gxa1, gxa2, gxa3, gxb0, gxb1, gxb2, gxb3;
    gxa0 = *(const f32x4*)(gp);
    gxa1 = *(const f32x4*)(gp + 128);
    gxa2 = *(const f32x4*)(gp + 256);
    gxa3 = *(const f32x4*)(gp + 384);

    for (int s = 0; s < TT - 2; s += 2) {
        STEP(0, 1, a, b, 1)
        STEP(1, 0, b, a, 1)
    }
    STEP(0, 1, a, b, 1)   // step 1022 (prefetches 1023)
    STEP(1, 0, b, a, 0)   // step 1023 (no prefetch)

    { f32x4 hv; hv[0] = h0; hv[1] = h1; hv[2] = h2; hv[3] = h3;
      *(f32x4*)(hn + (size_t)(b0g + beta) * HH + j0) = hv; }
    { f32x4 cv; cv[0] = c0; cv[1] = c1; cv[2] = c2; cv[3] = c3;
      *(f32x4*)(cn + (size_t)(b0g + beta) * HH + j0) = cv; }
}

// ---------------- launch ----------------
extern "C" void kernel_launch(void* const* d_in, const int* in_sizes, int n_in,
                              void* d_out, int out_size, void* d_ws, size_t ws_size,
                              hipStream_t stream) {
    const float* x   = (const float*)d_in[0];
    const float* wih = (const float*)d_in[1];
    const float* whh = (const float*)d_in[2];
    const float* bih = (const float*)d_in[3];
    const float* bhh = (const float*)d_in[4];
    float* out = (float*)d_out;

    // ws layout: [W_ih fp16 1MB][W_hh fp16 128KB][bsum 2KB pad->4KB][gx fp32 64MB]
    char* ws = (char*)d_ws;
    _Float16* wih_h = (_Float16*)ws;
    __half*   whh_h = (__half*)(ws + (size_t)(1 << 20));
    float*    bsum  = (float*)(ws + (size_t)(1 << 20) + (128 << 10));
    float*    gx    = (float*)(ws + (size_t)(1 << 20) + (128 << 10) + 4096);

    prep_kernel<<<(GG * DD) / 256, 256, 0, stream>>>(wih, whh, bih, bhh, wih_h, whh_h, bsum);
    gemm_gx<<<(BT / BM) * (GG / BN), 256, 0, stream>>>(x, wih_h, bsum, gx);

    float* hn = out + (size_t)BB * TT * HH;
    float* cn = hn + BB * HH;
    lstm_rec<<<2, 512, 0, stream>>>(gx, whh_h, out, hn, cn);
}